// Round 1
// baseline (11268.557 us; speedup 1.0000x reference)
//
#include <hip/hip_runtime.h>
#include <hip/hip_bf16.h>

#define B_  256
#define T_  1024
#define D_  256
#define H_  512
#define G_  2048   // 4*H
#define KT_ 768    // H + D

// ws layout (bytes)
#define WPACK_OFF 0                        // 2048*768*2 = 3145728
#define BIAS_OFF  3145728                  // 2048*4     = 8192
#define H0_OFF    (BIAS_OFF + 8192)        // 256*512*2  = 262144
#define H1_OFF    (H0_OFF + 262144)
#define C_OFF     (H1_OFF + 262144)        // 256*512*4  = 524288

typedef __attribute__((ext_vector_type(8))) short bf16x8;
typedef __attribute__((ext_vector_type(4))) float f32x4;

__device__ __forceinline__ unsigned short f2bf(float f) {
    unsigned int u = __float_as_uint(f);
    u = (u + 0x7fffu + ((u >> 16) & 1u)) >> 16;   // RNE
    return (unsigned short)u;
}
__device__ __forceinline__ float bf2f(unsigned short s) {
    return __uint_as_float(((unsigned int)s) << 16);
}
__device__ __forceinline__ float sigm(float v) { return 1.0f / (1.0f + __expf(-v)); }
__device__ __forceinline__ float tanh_(float v) { return 2.0f / (1.0f + __expf(-2.0f * v)) - 1.0f; }

// ---- prep: pack [W_hh | W_ih] rows into bf16 Wpack[2048][768] ----
__global__ __launch_bounds__(256) void build_wpack(const float* __restrict__ Whh,
                                                   const float* __restrict__ Wih,
                                                   unsigned short* __restrict__ wpack) {
    int idx = blockIdx.x * 256 + threadIdx.x;      // 0..196607, each = 8 elems
    int g = idx / 96, cc = idx % 96, k = cc * 8;
    const float* src = (k < H_) ? (Whh + (size_t)g * H_ + k)
                                : (Wih + (size_t)g * D_ + (k - H_));
    union { unsigned short us[8]; uint4 v; } u;
#pragma unroll
    for (int i = 0; i < 8; ++i) u.us[i] = f2bf(src[i]);
    *(uint4*)(wpack + (size_t)idx * 8) = u.v;
}

// ---- prep: zero h0/h1/c, build combined bias ----
__global__ __launch_bounds__(256) void init_misc(const float* __restrict__ bih,
                                                 const float* __restrict__ bhh,
                                                 float* __restrict__ bias,
                                                 unsigned int* __restrict__ zreg) {
    int gid = blockIdx.x * 256 + threadIdx.x;      // grid = 1024 blocks -> 262144 uints
    zreg[gid] = 0u;
    if (gid < G_) bias[gid] = bih[gid] + bhh[gid];
}

// ---- one timestep: gates = [h|x_t] @ Wpack^T + bias; cell update ----
// grid (4, 16): 64-row tile x 32-j tile. 256 threads = 4 waves.
__global__ __launch_bounds__(256) void lstm_step(const float* __restrict__ x,
                                                 const unsigned short* __restrict__ wpack,
                                                 const float* __restrict__ bias,
                                                 const unsigned short* __restrict__ hin,
                                                 unsigned short* __restrict__ hout,
                                                 float* __restrict__ cbuf,
                                                 int t) {
    __shared__ __align__(16) unsigned char As[64 * 1536];   // [64 rows][768 k] bf16, XOR-swizzled
    __shared__ __align__(16) unsigned char Ws[128 * 256];   // [128 n][128 k] bf16 chunk, swizzled

    const int tid = threadIdx.x;
    const int w = tid >> 6, lane = tid & 63;
    const int r0 = blockIdx.x * 64;
    const int j0 = blockIdx.y * 32;

    // stage A: h part (cols 0..512)
#pragma unroll
    for (int p = 0; p < 16; ++p) {
        int idx = p * 256 + tid;
        int row = idx >> 6, seg = idx & 63;
        uint4 v = *(const uint4*)(hin + (size_t)(r0 + row) * H_ + seg * 8);
        *(uint4*)(As + (((row * 1536) + seg * 16) ^ ((row & 7) << 4))) = v;
    }
    // stage A: x part (cols 512..768), f32 -> bf16
#pragma unroll
    for (int p = 0; p < 8; ++p) {
        int idx = p * 256 + tid;
        int row = idx >> 5, seg = idx & 31;
        const float* sp = x + ((size_t)(r0 + row) * T_ + t) * D_ + seg * 8;
        float4 a = *(const float4*)sp;
        float4 b = *(const float4*)(sp + 4);
        union { unsigned short us[8]; uint4 v; } u;
        u.us[0] = f2bf(a.x); u.us[1] = f2bf(a.y); u.us[2] = f2bf(a.z); u.us[3] = f2bf(a.w);
        u.us[4] = f2bf(b.x); u.us[5] = f2bf(b.y); u.us[6] = f2bf(b.z); u.us[7] = f2bf(b.w);
        *(uint4*)(As + (((row * 1536) + 1024 + seg * 16) ^ ((row & 7) << 4))) = u.v;
    }
    __syncthreads();

    f32x4 acc[8];   // [gate g (4)][jtile (2)] -> acc[g*2+jt]
#pragma unroll
    for (int i = 0; i < 8; ++i) acc[i] = (f32x4){0.f, 0.f, 0.f, 0.f};

    for (int kc = 0; kc < 6; ++kc) {
        // stage W chunk: n = g*32 + jj  ->  Wpack row g*512 + j0 + jj, k in [kc*128, +128)
#pragma unroll
        for (int p = 0; p < 8; ++p) {
            int idx = p * 256 + tid;
            int n = idx >> 4, seg = idx & 15;
            int g = n >> 5, jj = n & 31;
            uint4 v = *(const uint4*)(wpack + (size_t)(g * H_ + j0 + jj) * KT_ + kc * 128 + seg * 8);
            *(uint4*)(Ws + (((n * 256) + seg * 16) ^ ((n & 7) << 4))) = v;
        }
        __syncthreads();
#pragma unroll
        for (int ks = 0; ks < 4; ++ks) {
            int row = w * 16 + (lane & 15);
            int kb = (kc * 128 + ks * 32 + ((lane >> 4) * 8)) * 2;
            bf16x8 av = *(const bf16x8*)(As + ((row * 1536 + kb) ^ ((row & 7) << 4)));
            int kwb = (ks * 32 + ((lane >> 4) * 8)) * 2;
#pragma unroll
            for (int nt = 0; nt < 8; ++nt) {
                int n = (nt >> 1) * 32 + (nt & 1) * 16 + (lane & 15);
                bf16x8 bv = *(const bf16x8*)(Ws + ((n * 256 + kwb) ^ ((n & 7) << 4)));
                acc[nt] = __builtin_amdgcn_mfma_f32_16x16x32_bf16(av, bv, acc[nt], 0, 0, 0);
            }
        }
        __syncthreads();
    }

    // cell update: C layout col=lane&15 (j), row=(lane>>4)*4+reg (batch)
#pragma unroll
    for (int jt = 0; jt < 2; ++jt) {
        int jc = j0 + jt * 16 + (lane & 15);
        float bi = bias[jc], bf = bias[H_ + jc], bg = bias[2 * H_ + jc], bo = bias[3 * H_ + jc];
        f32x4 ai = acc[0 * 2 + jt];
        f32x4 af = acc[1 * 2 + jt];
        f32x4 ag = acc[2 * 2 + jt];
        f32x4 ao = acc[3 * 2 + jt];
#pragma unroll
        for (int reg = 0; reg < 4; ++reg) {
            int rb = r0 + w * 16 + ((lane >> 4) * 4) + reg;
            float I = sigm(ai[reg] + bi);
            float F = sigm(af[reg] + bf);
            float Gv = tanh_(ag[reg] + bg);
            float O = sigm(ao[reg] + bo);
            size_t ci = (size_t)rb * H_ + jc;
            float cn = F * cbuf[ci] + I * Gv;
            cbuf[ci] = cn;
            hout[ci] = f2bf(O * tanh_(cn));
        }
    }
}

// ---- final: out = sigmoid(h @ W_out^T + b_out), [256,2] ----
__global__ __launch_bounds__(256) void classify(const unsigned short* __restrict__ hbuf,
                                                const float* __restrict__ Wout,
                                                const float* __restrict__ bout,
                                                float* __restrict__ out) {
    int r = threadIdx.x;
    float a0 = 0.f, a1 = 0.f;
    for (int kk = 0; kk < H_ / 8; ++kk) {
        union { unsigned short us[8]; uint4 v; } u;
        u.v = *(const uint4*)(hbuf + (size_t)r * H_ + kk * 8);
#pragma unroll
        for (int i = 0; i < 8; ++i) {
            float hf = bf2f(u.us[i]);
            int k = kk * 8 + i;
            a0 += hf * Wout[k];
            a1 += hf * Wout[H_ + k];
        }
    }
    out[r * 2 + 0] = sigm(a0 + bout[0]);
    out[r * 2 + 1] = sigm(a1 + bout[1]);
}

extern "C" void kernel_launch(void* const* d_in, const int* in_sizes, int n_in,
                              void* d_out, int out_size, void* d_ws, size_t ws_size,
                              hipStream_t stream) {
    const float* x    = (const float*)d_in[0];
    const float* Wih  = (const float*)d_in[1];
    const float* Whh  = (const float*)d_in[2];
    const float* bih  = (const float*)d_in[3];
    const float* bhh  = (const float*)d_in[4];
    const float* Wout = (const float*)d_in[5];
    const float* bout = (const float*)d_in[6];
    float* out = (float*)d_out;
    char* ws = (char*)d_ws;

    unsigned short* wpack = (unsigned short*)(ws + WPACK_OFF);
    float*          bias  = (float*)(ws + BIAS_OFF);
    unsigned short* h0    = (unsigned short*)(ws + H0_OFF);
    unsigned short* h1    = (unsigned short*)(ws + H1_OFF);
    float*          cbuf  = (float*)(ws + C_OFF);

    build_wpack<<<768, 256, 0, stream>>>(Whh, Wih, wpack);
    init_misc<<<1024, 256, 0, stream>>>(bih, bhh, bias, (unsigned int*)(ws + H0_OFF));

    for (int t = 0; t < T_; ++t) {
        const unsigned short* hin = (t & 1) ? h1 : h0;
        unsigned short*      hout = (t & 1) ? h0 : h1;
        lstm_step<<<dim3(4, 16), 256, 0, stream>>>(x, wpack, bias, hin, hout, cbuf, t);
    }
    // after 1024 steps the final h is in h0
    classify<<<1, 256, 0, stream>>>(h0, Wout, bout, out);
}